// Round 3
// baseline (73.125 us; speedup 1.0000x reference)
//
#include <hip/hip_runtime.h>

// Problem constants
#define IMGX   144
#define PATCH  4
#define NPS    36      // patches per side
#define NTOKB  1296    // tokens per batch
#define ED     16      // embedding dim
#define NTOK   5184    // total tokens
#define RPW    4       // query rows per block (shared by all 4 waves)
#define BPB    324     // blocks per batch = 1296/RPW
#define NCHUNK 21      // chunks of 64 tokens per batch (last has 16 valid)
#define PREP_BLOCKS 21

// Module-scope scratch (load-time allocated; capture-safe, no d_ws).
__device__ float g_partial[PREP_BLOCKS];  // per-block input maxima
__device__ float g_norms[NTOK];           // per-token squared norms (raw x)

// Kernel 1: per-token squared norms + per-block max (unchanged; proven).
__global__ __launch_bounds__(256) void prep_kernel(const float* __restrict__ x) {
    __shared__ float wmax[4];
    const int tid = threadIdx.x;
    const int t = blockIdx.x * 256 + tid;
    float m = 0.0f;
    if (t < NTOK) {
        const float4* p = (const float4*)(x + t * ED);
        float4 a = p[0], bq = p[1], cq = p[2], dq = p[3];
        float ns = 0.0f;
        ns = fmaf(a.x, a.x, ns);  ns = fmaf(a.y, a.y, ns);
        ns = fmaf(a.z, a.z, ns);  ns = fmaf(a.w, a.w, ns);
        ns = fmaf(bq.x, bq.x, ns); ns = fmaf(bq.y, bq.y, ns);
        ns = fmaf(bq.z, bq.z, ns); ns = fmaf(bq.w, bq.w, ns);
        ns = fmaf(cq.x, cq.x, ns); ns = fmaf(cq.y, cq.y, ns);
        ns = fmaf(cq.z, cq.z, ns); ns = fmaf(cq.w, cq.w, ns);
        ns = fmaf(dq.x, dq.x, ns); ns = fmaf(dq.y, dq.y, ns);
        ns = fmaf(dq.z, dq.z, ns); ns = fmaf(dq.w, dq.w, ns);
        g_norms[t] = ns;
        // x >= 0 (uniform[0,1)), so 0-init max is safe
        m = fmaxf(fmaxf(fmaxf(a.x, a.y), fmaxf(a.z, a.w)),
                  fmaxf(fmaxf(fmaxf(bq.x, bq.y), fmaxf(bq.z, bq.w)),
                        fmaxf(fmaxf(fmaxf(cq.x, cq.y), fmaxf(cq.z, cq.w)),
                              fmaxf(fmaxf(dq.x, dq.y), fmaxf(dq.z, dq.w)))));
    }
#pragma unroll
    for (int s = 32; s; s >>= 1) m = fmaxf(m, __shfl_xor(m, s));
    if ((tid & 63) == 0) wmax[tid >> 6] = m;
    __syncthreads();
    if (tid == 0) {
        g_partial[blockIdx.x] = fmaxf(fmaxf(wmax[0], wmax[1]), fmaxf(wmax[2], wmax[3]));
    }
}

// Kernel 2: fused attention + merging.
// 1296 blocks x 256 threads; the 4 waves of a block SHARE the 4 query rows and
// SPLIT the 21 j-chunks as c === w (mod 4): 21 wave-chunk slots (3.6% waste)
// vs 24 for padded equal spans. No barriers / no LDS in the main loop; j-tokens
// read straight from global (L2-resident, 332KB working set) with 1-deep
// register prefetch.
//
// CODEGEN RULE (round-3 fix): every hot array is float4 with COMPILE-TIME
// constant indexing only -- named staging regs, macro-expanded dot/acc, and a
// butterfly with literal masks whose component select folds to a register
// lvalue. Round 1/2 runtime-indexed o[][] in the reduction, which demoted the
// main-loop accumulators to scratch (R1 evidence: VGPR_Count=92 for a >=160
// live set, 87% stall).
//
// Math: logit l_ij = s*(2*dot - n_j) - s*n_i, s = 1/(16*xmax^2). Row-constant
// cancels in softmax -> p = exp2(c2*dot - cn*n_j), c2 = 2s*log2e folded into
// the query registers, cn = s*log2e. p <= e, denom >= 1: no online softmax.
__global__ __launch_bounds__(256, 2) void attn_kernel(const float* __restrict__ x,
                                                      float* __restrict__ out) {
    __shared__ float redo[4][64];  // per-wave output partials (idx = r*16+d)
    __shared__ float redd[4][4];   // per-wave denominator partials (per row)

    const int tid  = threadIdx.x;
    const int lane = tid & 63;
    const int w    = tid >> 6;            // wave id -> chunk residue class
    const int blk  = blockIdx.x;          // 0..1295
    const int b    = blk / BPB;
    const int i0   = (blk - b * BPB) * RPW;

    const float* __restrict__ xb    = x + b * (NTOKB * ED);
    const float* __restrict__ norms = g_norms + b * NTOKB;

    // Global max from the 21 prep partials (full 64-lane butterfly).
    float pm = (lane < PREP_BLOCKS) ? g_partial[lane] : 0.0f;
#pragma unroll
    for (int sh = 32; sh; sh >>= 1) pm = fmaxf(pm, __shfl_xor(pm, sh));
    const float xmax = pm;
    const float s  = 1.0f / (16.0f * xmax * xmax);
    const float c2 = 2.0f * s * 1.4426950408889634f;  // 2s*log2(e) -> queries
    const float cf = s * 1.4426950408889634f;         // s*log2(e)  -> n_j

    // 4 query rows, pre-scaled by c2 (float4, literal indices only).
    float4 ti[4][4];
#pragma unroll
    for (int r = 0; r < 4; r++) {
        const float4* p = (const float4*)(xb + (i0 + r) * ED);
#pragma unroll
        for (int q = 0; q < 4; q++) {
            float4 a = p[q];
            a.x *= c2; a.y *= c2; a.z *= c2; a.w *= c2;
            ti[r][q] = a;
        }
    }

    float4 o[4][4];
#pragma unroll
    for (int r = 0; r < 4; r++)
#pragma unroll
        for (int q = 0; q < 4; q++) { o[r][q].x = 0.f; o[r][q].y = 0.f; o[r][q].z = 0.f; o[r][q].w = 0.f; }
    float den0 = 0.f, den1 = 0.f, den2 = 0.f, den3 = 0.f;

    // Prologue: load chunk w (always fully valid: chunks 0..3).
    float4 c0, c1, c2r, c3;
    float  njc;
    {
        const float4* p = (const float4*)(xb + (w * 64 + lane) * ED);
        c0 = p[0]; c1 = p[1]; c2r = p[2]; c3 = p[3];
        njc = norms[w * 64 + lane];
    }

#define DOT4(dd, A, C) dd = fmaf((A).x, (C).x, fmaf((A).y, (C).y, fmaf((A).z, (C).z, fmaf((A).w, (C).w, dd))))
#define ACCQ(r, q, C, E) \
    o[r][q].x = fmaf((E), (C).x, o[r][q].x); o[r][q].y = fmaf((E), (C).y, o[r][q].y); \
    o[r][q].z = fmaf((E), (C).z, o[r][q].z); o[r][q].w = fmaf((E), (C).w, o[r][q].w)
#define ACCR(r, E) ACCQ(r, 0, c0, E); ACCQ(r, 1, c1, E); ACCQ(r, 2, c2r, E); ACCQ(r, 3, c3, E)

    for (int t = 0; ; t++) {
        const int c    = w + 4 * t;       // current chunk (wave-uniform)
        const int cnx  = c + 4;           // next chunk for this wave
        const bool more = (cnx < NCHUNK); // wave-uniform branch

        // Prefetch next chunk; vmcnt wait lands after this iteration's compute.
        float4 n0, n1, n2, n3;
        float  njn = 0.f;
        if (more) {
            const int j  = cnx * 64 + lane;
            const int jc = (j < NTOKB) ? j : 0;  // clamp (chunk 20, lanes>=16)
            const float4* p = (const float4*)(xb + jc * ED);
            n0 = p[0]; n1 = p[1]; n2 = p[2]; n3 = p[3];
            njn = norms[jc];
        }

        const bool valid = (c * 64 + lane) < NTOKB;  // false only in chunk 20

        float d0 = 0.f, d1 = 0.f, d2 = 0.f, d3 = 0.f;
        DOT4(d0, ti[0][0], c0); DOT4(d0, ti[0][1], c1); DOT4(d0, ti[0][2], c2r); DOT4(d0, ti[0][3], c3);
        DOT4(d1, ti[1][0], c0); DOT4(d1, ti[1][1], c1); DOT4(d1, ti[1][2], c2r); DOT4(d1, ti[1][3], c3);
        DOT4(d2, ti[2][0], c0); DOT4(d2, ti[2][1], c1); DOT4(d2, ti[2][2], c2r); DOT4(d2, ti[2][3], c3);
        DOT4(d3, ti[3][0], c0); DOT4(d3, ti[3][1], c1); DOT4(d3, ti[3][2], c2r); DOT4(d3, ti[3][3], c3);

        const float cc = cf * njc;
        float e0 = __builtin_amdgcn_exp2f(d0 - cc);
        float e1 = __builtin_amdgcn_exp2f(d1 - cc);
        float e2 = __builtin_amdgcn_exp2f(d2 - cc);
        float e3 = __builtin_amdgcn_exp2f(d3 - cc);
        e0 = valid ? e0 : 0.f;
        e1 = valid ? e1 : 0.f;
        e2 = valid ? e2 : 0.f;
        e3 = valid ? e3 : 0.f;
        den0 += e0; den1 += e1; den2 += e2; den3 += e3;
        ACCR(0, e0); ACCR(1, e1); ACCR(2, e2); ACCR(3, e3);

        if (!more) break;
        c0 = n0; c1 = n1; c2r = n2; c3 = n3; njc = njn;
    }

    // Denominators: plain 64-lane butterfly (4 values).
#pragma unroll
    for (int sh = 32; sh; sh >>= 1) {
        den0 += __shfl_xor(den0, sh);
        den1 += __shfl_xor(den1, sh);
        den2 += __shfl_xor(den2, sh);
        den3 += __shfl_xor(den3, sh);
    }

    // Split-butterfly over the 64 flattened partials (idx = r*16 + q*4 + comp).
    // Six explicit stages with LITERAL masks; component select folds to a
    // register lvalue after the guaranteed literal-bound unroll (no runtime
    // indexing -> no scratch). After all stages lane L's V(0) = sum of idx L.
#define CMPSEL(v, c) ((c) == 0 ? (v).x : (c) == 1 ? (v).y : (c) == 2 ? (v).z : (v).w)
#define V(n) CMPSEL(o[(n) >> 4][((n) >> 2) & 3], (n) & 3)
#define BSTAGE(M)                                                   \
    {                                                               \
        const bool hi = (lane & (M)) != 0;                          \
        _Pragma("unroll")                                           \
        for (int k = 0; k < (M); k++) {                             \
            const float give = hi ? V(k) : V(k + (M));              \
            const float got  = __shfl_xor(give, (M));               \
            V(k) = (hi ? V(k + (M)) : V(k)) + got;                  \
        }                                                           \
    }
    BSTAGE(32) BSTAGE(16) BSTAGE(8) BSTAGE(4) BSTAGE(2) BSTAGE(1)

    redo[w][lane] = V(0);
    if (lane == 0) {
        redd[w][0] = den0; redd[w][1] = den1; redd[w][2] = den2; redd[w][3] = den3;
    }
    __syncthreads();

    if (w == 0) {
        const float v = redo[0][lane] + redo[1][lane] + redo[2][lane] + redo[3][lane];
        const int r = lane >> 4;
        const int d = lane & 15;
        const float den = redd[0][r] + redd[1][r] + redd[2][r] + redd[3][r];
        const float val = v / den;

        // Merging permutation: row i -> patch (by,bx); d=(ky,kx) -> pixel.
        const int i  = i0 + r;
        const int by = i / NPS;
        const int bx = i - by * NPS;
        out[b * (IMGX * IMGX) + (by * PATCH + (d >> 2)) * IMGX + bx * PATCH + (d & 3)] = val;
    }
#undef V
#undef CMPSEL
#undef BSTAGE
#undef DOT4
#undef ACCQ
#undef ACCR
}

extern "C" void kernel_launch(void* const* d_in, const int* in_sizes, int n_in,
                              void* d_out, int out_size, void* d_ws, size_t ws_size,
                              hipStream_t stream) {
    const float* x = (const float*)d_in[0];  // f32 (4,1,144,144)
    float* out = (float*)d_out;              // f32 (4,1,144,144)
    (void)d_ws; (void)ws_size;

    hipLaunchKernelGGL(prep_kernel, dim3(PREP_BLOCKS), dim3(256), 0, stream, x);
    hipLaunchKernelGGL(attn_kernel, dim3(NTOKB), dim3(256), 0, stream, x, out);
}